// Round 10
// baseline (235.458 us; speedup 1.0000x reference)
//
#include <hip/hip_runtime.h>
#include <hip/hip_bf16.h>
#include <hip/hip_cooperative_groups.h>

namespace cg = cooperative_groups;

// Problem constants: B=32, T=256, D=512, P=20
#define BB 32
#define TT 256
#define DD 512
#define PP 20
#define EPSF 1e-12f
#define BTP (BB * TT * PP)   // 163840

typedef __attribute__((ext_vector_type(8))) short short8;
typedef __attribute__((ext_vector_type(4))) float f32x4;

__device__ inline unsigned short f2bf(float f) {
    unsigned u = __float_as_uint(f);
    u += 0x7fffu + ((u >> 16) & 1u);          // round-to-nearest-even
    return (unsigned short)(u >> 16);
}
// HW packed f32x2 -> bf16x2 (v_cvt_pk_bf16_f32 on gfx950), RNE.
__device__ inline unsigned pk2(float lo, float hi) {
    __hip_bfloat162 h = __float22bfloat162_rn(float2{lo, hi});
    union { __hip_bfloat162 h; unsigned u; } c;
    c.h = h;
    return c.u;
}
__device__ inline float bf2f(unsigned s) {    // s = 16-bit bf16 payload
    return __uint_as_float(s << 16);
}

union U8 { short8 s; uint4 u; };

// Shared-memory overlay for the phases (max ~14.4 KB)
union SMem {
    struct {                                  // phases 2 & 3 (GEMMs)
        unsigned short As[64 * 40];
        unsigned short Bs[64 * 40];
        float qsum[64];
    } g;
    struct {                                  // phase 4 (persp)
        float qs[DD];                         // invq table for this batch
        float ps[2][64][24];                  // split-K partials per half-tile
    } p;
};

// ---------------------------------------------------------------------------
// Persistent cooperative kernel: all 4 stages, grid 256 x 256 (1 block/CU).
//   P1: row norms -> na_bf, nb_bf; zero q; build W2
//   P2: G = nb nb^T           (2 tiles/block)
//   P3: H = G na, q += na*H   (4 tiles/block, inline B-transpose staging)
//   P4: persp outputs          (2 tiles/block, split-K over 2 waves each)
// All arithmetic verbatim from the 4-kernel R9 version -> bit-identical.
// ---------------------------------------------------------------------------
__global__ __launch_bounds__(256)
void k_mega(const float* __restrict__ a, const float* __restrict__ b,
            const float* __restrict__ W,
            unsigned short* __restrict__ na_bf,
            unsigned short* __restrict__ nb_bf,
            unsigned short* __restrict__ G,
            unsigned short* __restrict__ H,
            float* __restrict__ q, unsigned short* __restrict__ W2,
            float* __restrict__ out) {
    __shared__ __align__(16) SMem sm;
    cg::grid_group grid = cg::this_grid();

    const int tid  = threadIdx.x;
    const int wave = tid >> 6;
    const int lane = tid & 63;
    const int quad = lane >> 4, ln = lane & 15;

    // ---------------- Phase 1: prep ----------------
    {
        const int w = blockIdx.x * 4 + wave;           // 0..1023
#pragma unroll
        for (int r8 = 0; r8 < 8; ++r8) {
            const int row = w * 8 + r8;                // 0..8191
            const float4* pa = (const float4*)(a + (size_t)row * DD);
            const float4* pb = (const float4*)(b + (size_t)row * DD);
            float4 a0 = pa[2 * lane], a1 = pa[2 * lane + 1];
            float4 b0 = pb[2 * lane], b1 = pb[2 * lane + 1];
            float sa = a0.x * a0.x + a0.y * a0.y + a0.z * a0.z + a0.w * a0.w
                     + a1.x * a1.x + a1.y * a1.y + a1.z * a1.z + a1.w * a1.w;
            float sb = b0.x * b0.x + b0.y * b0.y + b0.z * b0.z + b0.w * b0.w
                     + b1.x * b1.x + b1.y * b1.y + b1.z * b1.z + b1.w * b1.w;
#pragma unroll
            for (int off = 1; off < 64; off <<= 1) {
                sa += __shfl_xor(sa, off);
                sb += __shfl_xor(sb, off);
            }
            const float ia_ = rsqrtf(fmaxf(sa, EPSF));
            const float ib_ = rsqrtf(fmaxf(sb, EPSF));
            uint4 oa, ob;
            oa.x = pk2(a0.x * ia_, a0.y * ia_);
            oa.y = pk2(a0.z * ia_, a0.w * ia_);
            oa.z = pk2(a1.x * ia_, a1.y * ia_);
            oa.w = pk2(a1.z * ia_, a1.w * ia_);
            ob.x = pk2(b0.x * ib_, b0.y * ib_);
            ob.y = pk2(b0.z * ib_, b0.w * ib_);
            ob.z = pk2(b1.x * ib_, b1.y * ib_);
            ob.w = pk2(b1.z * ib_, b1.w * ib_);
            *(uint4*)(na_bf + (size_t)row * DD + 8 * lane) = oa;
            *(uint4*)(nb_bf + (size_t)row * DD + 8 * lane) = ob;
            if (lane < 2) {
                const int i2 = 2 * row + lane;         // covers 0..16383 = B*D
                q[i2] = 0.f;
                const float w2 = (i2 < PP * DD) ? W[i2] : 0.f;
                W2[i2] = f2bf(w2 * w2);
            }
        }
    }
    grid.sync();

    // ---------------- Phase 2: G = nb nb^T (2 tiles/block) ----------------
    {
        const int wm = wave >> 1, wn = wave & 1;
        const int lr = tid >> 2;          // 0..63
        const int c8 = (tid & 3) * 8;     // 0..24
#pragma unroll
        for (int it = 0; it < 2; ++it) {
            const int tt = blockIdx.x * 2 + it;        // 0..511
            const int bz = tt >> 4;
            const int t0 = ((tt >> 2) & 3) * 64;
            const int s0 = (tt & 3) * 64;
            const unsigned short* nbb = nb_bf + (size_t)bz * TT * DD;

            f32x4 acc[2][2];
#pragma unroll
            for (int i = 0; i < 2; ++i)
#pragma unroll
                for (int j = 0; j < 2; ++j)
#pragma unroll
                    for (int r = 0; r < 4; ++r) acc[i][j][r] = 0.f;

            for (int k0 = 0; k0 < DD; k0 += 32) {
                *(uint4*)&sm.g.As[lr * 40 + c8] =
                    *(const uint4*)(nbb + (size_t)(t0 + lr) * DD + k0 + c8);
                *(uint4*)&sm.g.Bs[lr * 40 + c8] =
                    *(const uint4*)(nbb + (size_t)(s0 + lr) * DD + k0 + c8);
                __syncthreads();
                short8 af[2], bf[2];
                af[0] = *(const short8*)&sm.g.As[(wm * 32 + ln) * 40 + quad * 8];
                af[1] = *(const short8*)&sm.g.As[(wm * 32 + 16 + ln) * 40 + quad * 8];
                bf[0] = *(const short8*)&sm.g.Bs[(wn * 32 + ln) * 40 + quad * 8];
                bf[1] = *(const short8*)&sm.g.Bs[(wn * 32 + 16 + ln) * 40 + quad * 8];
#pragma unroll
                for (int i = 0; i < 2; ++i)
#pragma unroll
                    for (int j = 0; j < 2; ++j)
                        acc[i][j] = __builtin_amdgcn_mfma_f32_16x16x32_bf16(
                            af[i], bf[j], acc[i][j], 0, 0, 0);
                __syncthreads();
            }
            unsigned short* Gb = G + (size_t)bz * TT * TT;
#pragma unroll
            for (int i = 0; i < 2; ++i)
#pragma unroll
                for (int j = 0; j < 2; ++j) {
                    const int col = s0 + wn * 32 + j * 16 + ln;
                    const int row0 = t0 + wm * 32 + i * 16 + quad * 4;
#pragma unroll
                    for (int r = 0; r < 4; r += 2) {
                        const unsigned pk = pk2(acc[i][j][r], acc[i][j][r + 1]);
                        Gb[(size_t)(row0 + r) * TT + col] = (unsigned short)pk;
                        Gb[(size_t)(row0 + r + 1) * TT + col] = (unsigned short)(pk >> 16);
                    }
                }
        }
    }
    grid.sync();

    // ---------------- Phase 3: H = G na, q accumulate (4 tiles/block) ------
    {
        const int wm = wave >> 1, wn = wave & 1;
        const int lr = tid >> 2;          // 0..63  (A staging)
        const int c8 = (tid & 3) * 8;
        const int kr = tid >> 3;          // 0..31  (B staging)
        const int e8 = (tid & 7) * 8;
#pragma unroll
        for (int it = 0; it < 4; ++it) {
            const int tt = blockIdx.x * 4 + it;        // 0..1023
            const int bz = tt >> 5;
            const int t0 = ((tt >> 3) & 3) * 64;
            const int e0 = (tt & 7) * 64;
            const unsigned short* Gb  = G     + (size_t)bz * TT * TT;
            const unsigned short* nab = na_bf + (size_t)bz * TT * DD;

            f32x4 acc[2][2];
#pragma unroll
            for (int i = 0; i < 2; ++i)
#pragma unroll
                for (int j = 0; j < 2; ++j)
#pragma unroll
                    for (int r = 0; r < 4; ++r) acc[i][j][r] = 0.f;

            for (int k0 = 0; k0 < TT; k0 += 32) {
                *(uint4*)&sm.g.As[lr * 40 + c8] =
                    *(const uint4*)(Gb + (size_t)(t0 + lr) * TT + k0 + c8);
                {   // inline transpose of na into Bs[e][k]
                    uint4 v = *(const uint4*)(nab + (size_t)(k0 + kr) * DD + e0 + e8);
                    sm.g.Bs[(e8 + 0) * 40 + kr] = (unsigned short)(v.x);
                    sm.g.Bs[(e8 + 1) * 40 + kr] = (unsigned short)(v.x >> 16);
                    sm.g.Bs[(e8 + 2) * 40 + kr] = (unsigned short)(v.y);
                    sm.g.Bs[(e8 + 3) * 40 + kr] = (unsigned short)(v.y >> 16);
                    sm.g.Bs[(e8 + 4) * 40 + kr] = (unsigned short)(v.z);
                    sm.g.Bs[(e8 + 5) * 40 + kr] = (unsigned short)(v.z >> 16);
                    sm.g.Bs[(e8 + 6) * 40 + kr] = (unsigned short)(v.w);
                    sm.g.Bs[(e8 + 7) * 40 + kr] = (unsigned short)(v.w >> 16);
                }
                __syncthreads();
                short8 af[2], bf[2];
                af[0] = *(const short8*)&sm.g.As[(wm * 32 + ln) * 40 + quad * 8];
                af[1] = *(const short8*)&sm.g.As[(wm * 32 + 16 + ln) * 40 + quad * 8];
                bf[0] = *(const short8*)&sm.g.Bs[(wn * 32 + ln) * 40 + quad * 8];
                bf[1] = *(const short8*)&sm.g.Bs[(wn * 32 + 16 + ln) * 40 + quad * 8];
#pragma unroll
                for (int i = 0; i < 2; ++i)
#pragma unroll
                    for (int j = 0; j < 2; ++j)
                        acc[i][j] = __builtin_amdgcn_mfma_f32_16x16x32_bf16(
                            af[i], bf[j], acc[i][j], 0, 0, 0);
                __syncthreads();
            }

            if (tid < 64) sm.g.qsum[tid] = 0.f;
            __syncthreads();

            unsigned short* Hb = H + (size_t)bz * TT * DD;
#pragma unroll
            for (int j = 0; j < 2; ++j) {
                const int col = e0 + wn * 32 + j * 16 + ln;
                float qp = 0.f;
#pragma unroll
                for (int i = 0; i < 2; ++i) {
                    const int row0 = t0 + wm * 32 + i * 16 + quad * 4;
#pragma unroll
                    for (int r = 0; r < 4; r += 2) {
                        const float hv0 = acc[i][j][r];
                        const float hv1 = acc[i][j][r + 1];
                        const unsigned pk = pk2(hv0, hv1);
                        Hb[(size_t)(row0 + r) * DD + col] = (unsigned short)pk;
                        Hb[(size_t)(row0 + r + 1) * DD + col] = (unsigned short)(pk >> 16);
                        qp = fmaf(bf2f(nab[(size_t)(row0 + r) * DD + col]), hv0, qp);
                        qp = fmaf(bf2f(nab[(size_t)(row0 + r + 1) * DD + col]), hv1, qp);
                    }
                }
                qp += __shfl_xor(qp, 16);
                qp += __shfl_xor(qp, 32);
                if (quad == 0) atomicAdd(&sm.g.qsum[wn * 32 + j * 16 + ln], qp);
            }
            __syncthreads();
            if (tid < 64) atomicAdd(q + bz * DD + e0 + tid, sm.g.qsum[tid]);
            __syncthreads();
        }
    }
    grid.sync();

    // ---------------- Phase 4: persp (2 tiles/block, split-K x2) ----------
    {
        const int half = wave >> 1;       // which 16-row tile
        const int wv   = wave & 1;        // split-K half
        const int tt   = blockIdx.x * 2 + half;        // 0..511
        const int bb   = tt >> 4;                      // same for both halves
        const int r0   = (tt & 15) * 16;
        const size_t rowbase = ((size_t)bb * TT + r0 + ln) * DD;

        {   // invq table (both halves share bb)
            const float* qb = q + (size_t)bb * DD;
            float2 v = *(const float2*)(qb + 2 * tid);
            sm.p.qs[2 * tid + 0] = rsqrtf(fmaxf(v.x, EPSF));
            sm.p.qs[2 * tid + 1] = rsqrtf(fmaxf(v.y, EPSF));
        }
        __syncthreads();

        f32x4 s1[2], s2[2], s3[2];
#pragma unroll
        for (int j = 0; j < 2; ++j)
#pragma unroll
            for (int r = 0; r < 4; ++r) { s1[j][r] = 0.f; s2[j][r] = 0.f; s3[j][r] = 0.f; }

        const int kbeg = wv * 256;
        for (int k0 = kbeg; k0 < kbeg + 256; k0 += 32) {
            const int k = k0 + quad * 8;
            uint4 au = *(const uint4*)(na_bf + rowbase + k);
            uint4 hu = *(const uint4*)(H + rowbase + k);
            float4 q0 = *(const float4*)&sm.p.qs[k];
            float4 q1 = *(const float4*)&sm.p.qs[k + 4];
            const float av[8] = {bf2f(au.x & 0xffffu), bf2f(au.x >> 16),
                                 bf2f(au.y & 0xffffu), bf2f(au.y >> 16),
                                 bf2f(au.z & 0xffffu), bf2f(au.z >> 16),
                                 bf2f(au.w & 0xffffu), bf2f(au.w >> 16)};
            const float qv[8] = {q0.x, q0.y, q0.z, q0.w, q1.x, q1.y, q1.z, q1.w};
            float hv[8] = {bf2f(hu.x & 0xffffu), bf2f(hu.x >> 16),
                           bf2f(hu.y & 0xffffu), bf2f(hu.y >> 16),
                           bf2f(hu.z & 0xffffu), bf2f(hu.z >> 16),
                           bf2f(hu.w & 0xffffu), bf2f(hu.w >> 16)};
#pragma unroll
            for (int t = 0; t < 8; ++t) hv[t] *= qv[t];
            U8 ah, aa, hh;
            ah.u.x = pk2(av[0] * hv[0], av[1] * hv[1]);
            ah.u.y = pk2(av[2] * hv[2], av[3] * hv[3]);
            ah.u.z = pk2(av[4] * hv[4], av[5] * hv[5]);
            ah.u.w = pk2(av[6] * hv[6], av[7] * hv[7]);
            aa.u.x = pk2(av[0] * av[0], av[1] * av[1]);
            aa.u.y = pk2(av[2] * av[2], av[3] * av[3]);
            aa.u.z = pk2(av[4] * av[4], av[5] * av[5]);
            aa.u.w = pk2(av[6] * av[6], av[7] * av[7]);
            hh.u.x = pk2(hv[0] * hv[0], hv[1] * hv[1]);
            hh.u.y = pk2(hv[2] * hv[2], hv[3] * hv[3]);
            hh.u.z = pk2(hv[4] * hv[4], hv[5] * hv[5]);
            hh.u.w = pk2(hv[6] * hv[6], hv[7] * hv[7]);
            short8 bw0 = *(const short8*)(W2 + (size_t)ln * DD + k);
            short8 bw1 = *(const short8*)(W2 + (size_t)(16 + ln) * DD + k);
            s1[0] = __builtin_amdgcn_mfma_f32_16x16x32_bf16(ah.s, bw0, s1[0], 0, 0, 0);
            s1[1] = __builtin_amdgcn_mfma_f32_16x16x32_bf16(ah.s, bw1, s1[1], 0, 0, 0);
            s2[0] = __builtin_amdgcn_mfma_f32_16x16x32_bf16(aa.s, bw0, s2[0], 0, 0, 0);
            s2[1] = __builtin_amdgcn_mfma_f32_16x16x32_bf16(aa.s, bw1, s2[1], 0, 0, 0);
            s3[0] = __builtin_amdgcn_mfma_f32_16x16x32_bf16(hh.s, bw0, s3[0], 0, 0, 0);
            s3[1] = __builtin_amdgcn_mfma_f32_16x16x32_bf16(hh.s, bw1, s3[1], 0, 0, 0);
        }

        if (wv == 1) {
#pragma unroll
            for (int j = 0; j < 2; ++j)
#pragma unroll
                for (int r = 0; r < 4; ++r) {
                    sm.p.ps[half][lane][j * 4 + r]      = s1[j][r];
                    sm.p.ps[half][lane][8 + j * 4 + r]  = s2[j][r];
                    sm.p.ps[half][lane][16 + j * 4 + r] = s3[j][r];
                }
        }
        __syncthreads();
        if (wv == 0) {
#pragma unroll
            for (int j = 0; j < 2; ++j) {
                const int p = j * 16 + ln;
                if (p < PP) {
#pragma unroll
                    for (int r = 0; r < 4; ++r) {
                        const float v1 = s1[j][r] + sm.p.ps[half][lane][j * 4 + r];
                        const float v2 = s2[j][r] + sm.p.ps[half][lane][8 + j * 4 + r];
                        const float v3 = s3[j][r] + sm.p.ps[half][lane][16 + j * 4 + r];
                        const size_t row = (size_t)bb * TT + r0 + quad * 4 + r;
                        const float v = v1 * rsqrtf(fmaxf(v2, EPSF))
                                           * rsqrtf(fmaxf(v3, EPSF));
                        out[row * PP + p] = v;
                        out[(size_t)BTP + row * PP + p] = v;
                    }
                }
            }
        }
    }
}

// ---------------------------------------------------------------------------
extern "C" void kernel_launch(void* const* d_in, const int* in_sizes, int n_in,
                              void* d_out, int out_size, void* d_ws, size_t ws_size,
                              hipStream_t stream) {
    (void)in_sizes; (void)n_in; (void)out_size; (void)ws_size;
    const float* a = (const float*)d_in[0];   // (B,T,D)
    const float* b = (const float*)d_in[1];   // (B,T,D)
    const float* W = (const float*)d_in[2];   // (P,D)
    float* out = (float*)d_out;

    char* ws = (char*)d_ws;
    unsigned short* nb_bf = (unsigned short*)ws;                       // 8 MB
    unsigned short* na_bf = (unsigned short*)(ws + (8u << 20));        // 8 MB
    unsigned short* G_bf  = (unsigned short*)(ws + (16u << 20));       // 4 MB
    unsigned short* H_bf  = (unsigned short*)(ws + (20u << 20));       // 8 MB
    float* q     = (float*)(ws + (28u << 20));                         // 64 KB
    unsigned short* W2 = (unsigned short*)(ws + (28u << 20) + (64u << 10)); // 32 KB

    void* args[] = {(void*)&a, (void*)&b, (void*)&W,
                    (void*)&na_bf, (void*)&nb_bf, (void*)&G_bf, (void*)&H_bf,
                    (void*)&q, (void*)&W2, (void*)&out};
    hipLaunchCooperativeKernel((const void*)k_mega, dim3(256), dim3(256),
                               args, 0, stream);
}

// Round 11
// 111.561 us; speedup vs baseline: 2.1106x; 2.1106x over previous
//
#include <hip/hip_runtime.h>
#include <hip/hip_bf16.h>

// Problem constants: B=32, T=256, D=512, P=20
#define BB 32
#define TT 256
#define DD 512
#define PP 20
#define EPSF 1e-12f
#define BTP (BB * TT * PP)   // 163840

typedef __attribute__((ext_vector_type(8))) short short8;
typedef __attribute__((ext_vector_type(4))) float f32x4;

__device__ inline unsigned short f2bf(float f) {
    unsigned u = __float_as_uint(f);
    u += 0x7fffu + ((u >> 16) & 1u);          // round-to-nearest-even
    return (unsigned short)(u >> 16);
}
// HW packed f32x2 -> bf16x2 (v_cvt_pk_bf16_f32 on gfx950), RNE — bit-identical
// to f2bf pairs.  lo -> low 16, hi -> high 16.
__device__ inline unsigned pk2(float lo, float hi) {
    __hip_bfloat162 h = __float22bfloat162_rn(float2{lo, hi});
    union { __hip_bfloat162 h; unsigned u; } c;
    c.h = h;
    return c.u;
}
__device__ inline float bf2f(unsigned s) {    // s = 16-bit bf16 payload
    return __uint_as_float(s << 16);
}

union U8 { short8 s; uint4 u; };

// ---------------------------------------------------------------------------
// K1: per-row inverse L2 norms; emit nb_bf = bf16(b*inv_b) and
// na_bf = bf16(a*inv_a), row-major.  Also zero q and build W2 = bf16(W^2)
// padded to 32x512.  grid = B*T/4 blocks of 256 thr (1 wave = 1 row).
// ---------------------------------------------------------------------------
__global__ __launch_bounds__(256)
void k_prep(const float* __restrict__ a, const float* __restrict__ b,
            const float* __restrict__ W,
            unsigned short* __restrict__ na_bf,
            unsigned short* __restrict__ nb_bf,
            float* __restrict__ q, unsigned short* __restrict__ W2) {
    const int row  = blockIdx.x * 4 + (threadIdx.x >> 6);
    const int lane = threadIdx.x & 63;
    const float4* pa = (const float4*)(a + (size_t)row * DD);
    const float4* pb = (const float4*)(b + (size_t)row * DD);
    float4 a0 = pa[2 * lane], a1 = pa[2 * lane + 1];
    float4 b0 = pb[2 * lane], b1 = pb[2 * lane + 1];
    float sa = a0.x * a0.x + a0.y * a0.y + a0.z * a0.z + a0.w * a0.w
             + a1.x * a1.x + a1.y * a1.y + a1.z * a1.z + a1.w * a1.w;
    float sb = b0.x * b0.x + b0.y * b0.y + b0.z * b0.z + b0.w * b0.w
             + b1.x * b1.x + b1.y * b1.y + b1.z * b1.z + b1.w * b1.w;
#pragma unroll
    for (int off = 1; off < 64; off <<= 1) {
        sa += __shfl_xor(sa, off);
        sb += __shfl_xor(sb, off);
    }
    const float ia_ = rsqrtf(fmaxf(sa, EPSF));
    const float ib_ = rsqrtf(fmaxf(sb, EPSF));
    uint4 oa, ob;
    oa.x = pk2(a0.x * ia_, a0.y * ia_);
    oa.y = pk2(a0.z * ia_, a0.w * ia_);
    oa.z = pk2(a1.x * ia_, a1.y * ia_);
    oa.w = pk2(a1.z * ia_, a1.w * ia_);
    ob.x = pk2(b0.x * ib_, b0.y * ib_);
    ob.y = pk2(b0.z * ib_, b0.w * ib_);
    ob.z = pk2(b1.x * ib_, b1.y * ib_);
    ob.w = pk2(b1.z * ib_, b1.w * ib_);
    *(uint4*)(na_bf + (size_t)row * DD + 8 * lane) = oa;
    *(uint4*)(nb_bf + (size_t)row * DD + 8 * lane) = ob;
    if (lane < 2) {
        const int i2 = 2 * row + lane;       // covers 0 .. 16383 = B*D
        q[i2] = 0.f;
        const float w = (i2 < PP * DD) ? W[i2] : 0.f;
        W2[i2] = f2bf(w * w);
    }
}

// ---------------------------------------------------------------------------
// K2: G GEMM (G[b][t][s] = bf16 sum_d nb[t,d] nb[s,d], MFMA 16x16x32,
// 64x64 tile, BK=32).  grid: (4, 4, 32), 256 thr.
// ---------------------------------------------------------------------------
__global__ __launch_bounds__(256)
void k_gemm_g(const unsigned short* __restrict__ nb,
              unsigned short* __restrict__ G) {
    const int bz  = blockIdx.z;
    const int tid = threadIdx.x;
    const int t0 = blockIdx.y * 64;
    const int s0 = blockIdx.x * 64;
    __shared__ __align__(16) unsigned short As[64 * 40];
    __shared__ __align__(16) unsigned short Bs[64 * 40];

    const int wave = tid >> 6, lane = tid & 63;
    const int quad = lane >> 4, ln = lane & 15;
    const int wm = wave >> 1, wn = wave & 1;

    const unsigned short* nbb = nb + (size_t)bz * TT * DD;

    const int lr = tid >> 2;          // 0..63
    const int c8 = (tid & 3) * 8;     // 0..24

    f32x4 acc[2][2];
#pragma unroll
    for (int i = 0; i < 2; ++i)
#pragma unroll
        for (int j = 0; j < 2; ++j)
#pragma unroll
            for (int r = 0; r < 4; ++r) acc[i][j][r] = 0.f;

    for (int k0 = 0; k0 < DD; k0 += 32) {
        *(uint4*)&As[lr * 40 + c8] =
            *(const uint4*)(nbb + (size_t)(t0 + lr) * DD + k0 + c8);
        *(uint4*)&Bs[lr * 40 + c8] =
            *(const uint4*)(nbb + (size_t)(s0 + lr) * DD + k0 + c8);
        __syncthreads();
        short8 af[2], bf[2];
        af[0] = *(const short8*)&As[(wm * 32 + ln) * 40 + quad * 8];
        af[1] = *(const short8*)&As[(wm * 32 + 16 + ln) * 40 + quad * 8];
        bf[0] = *(const short8*)&Bs[(wn * 32 + ln) * 40 + quad * 8];
        bf[1] = *(const short8*)&Bs[(wn * 32 + 16 + ln) * 40 + quad * 8];
#pragma unroll
        for (int i = 0; i < 2; ++i)
#pragma unroll
            for (int j = 0; j < 2; ++j)
                acc[i][j] = __builtin_amdgcn_mfma_f32_16x16x32_bf16(
                    af[i], bf[j], acc[i][j], 0, 0, 0);
        __syncthreads();
    }
    unsigned short* Gb = G + (size_t)bz * TT * TT;
#pragma unroll
    for (int i = 0; i < 2; ++i)
#pragma unroll
        for (int j = 0; j < 2; ++j) {
            const int col = s0 + wn * 32 + j * 16 + ln;
            const int row0 = t0 + wm * 32 + i * 16 + quad * 4;
#pragma unroll
            for (int r = 0; r < 4; r += 2) {
                const unsigned pk = pk2(acc[i][j][r], acc[i][j][r + 1]);
                Gb[(size_t)(row0 + r) * TT + col] = (unsigned short)pk;
                Gb[(size_t)(row0 + r + 1) * TT + col] = (unsigned short)(pk >> 16);
            }
        }
}

// ---------------------------------------------------------------------------
// K3: H[b][t][e] = sum_s G[t,s] * na[s,e]  (BK=32).  B-operand is transposed
// INLINE during LDS staging (reads row-major na, scatters ds_write_b16 into
// Bs[e][k]) — same Bs bits & accumulation order as a pre-materialized naT, so
// the result is bit-identical; no naT buffer or transpose kernel.
// H stored bf16; fused epilogue q[b][e] += sum_t na[t,e]*H[t,e] (atomics).
// grid: (D/64, T/64, B), 256 thr.
// ---------------------------------------------------------------------------
__global__ __launch_bounds__(256)
void k_gemm_h(const unsigned short* __restrict__ G,
              const unsigned short* __restrict__ na,
              unsigned short* __restrict__ H, float* __restrict__ q) {
    const int bz = blockIdx.z;
    const int t0 = blockIdx.y * 64;
    const int e0 = blockIdx.x * 64;
    __shared__ __align__(16) unsigned short As[64 * 40];
    __shared__ __align__(16) unsigned short Bs[64 * 40];
    __shared__ float qsum[64];

    const int tid  = threadIdx.x;
    const int wave = tid >> 6, lane = tid & 63;
    const int quad = lane >> 4, ln = lane & 15;
    const int wm = wave >> 1, wn = wave & 1;

    const unsigned short* Gb  = G  + (size_t)bz * TT * TT;
    const unsigned short* nab = na + (size_t)bz * TT * DD;

    const int lr = tid >> 2;          // 0..63  (A staging row)
    const int c8 = (tid & 3) * 8;     // 0..24  (A staging col)
    const int kr = tid >> 3;          // 0..31  (B staging: na row within k-tile)
    const int e8 = (tid & 7) * 8;     // 0..56  (B staging: e offset)

    f32x4 acc[2][2];
#pragma unroll
    for (int i = 0; i < 2; ++i)
#pragma unroll
        for (int j = 0; j < 2; ++j)
#pragma unroll
            for (int r = 0; r < 4; ++r) acc[i][j][r] = 0.f;

    for (int k0 = 0; k0 < TT; k0 += 32) {
        // A: G rows, K-contiguous copy
        *(uint4*)&As[lr * 40 + c8] =
            *(const uint4*)(Gb + (size_t)(t0 + lr) * TT + k0 + c8);
        // B: inline transpose — load 8 consecutive e from na row (k0+kr),
        // scatter to Bs[e][k]
        {
            uint4 v = *(const uint4*)(nab + (size_t)(k0 + kr) * DD + e0 + e8);
            Bs[(e8 + 0) * 40 + kr] = (unsigned short)(v.x);
            Bs[(e8 + 1) * 40 + kr] = (unsigned short)(v.x >> 16);
            Bs[(e8 + 2) * 40 + kr] = (unsigned short)(v.y);
            Bs[(e8 + 3) * 40 + kr] = (unsigned short)(v.y >> 16);
            Bs[(e8 + 4) * 40 + kr] = (unsigned short)(v.z);
            Bs[(e8 + 5) * 40 + kr] = (unsigned short)(v.z >> 16);
            Bs[(e8 + 6) * 40 + kr] = (unsigned short)(v.w);
            Bs[(e8 + 7) * 40 + kr] = (unsigned short)(v.w >> 16);
        }
        __syncthreads();
        short8 af[2], bf[2];
        af[0] = *(const short8*)&As[(wm * 32 + ln) * 40 + quad * 8];
        af[1] = *(const short8*)&As[(wm * 32 + 16 + ln) * 40 + quad * 8];
        bf[0] = *(const short8*)&Bs[(wn * 32 + ln) * 40 + quad * 8];
        bf[1] = *(const short8*)&Bs[(wn * 32 + 16 + ln) * 40 + quad * 8];
#pragma unroll
        for (int i = 0; i < 2; ++i)
#pragma unroll
            for (int j = 0; j < 2; ++j)
                acc[i][j] = __builtin_amdgcn_mfma_f32_16x16x32_bf16(
                    af[i], bf[j], acc[i][j], 0, 0, 0);
        __syncthreads();
    }

    if (tid < 64) qsum[tid] = 0.f;
    __syncthreads();

    unsigned short* Hb = H + (size_t)bz * TT * DD;
#pragma unroll
    for (int j = 0; j < 2; ++j) {
        const int col = e0 + wn * 32 + j * 16 + ln;
        float qp = 0.f;
#pragma unroll
        for (int i = 0; i < 2; ++i) {
            const int row0 = t0 + wm * 32 + i * 16 + quad * 4;
#pragma unroll
            for (int r = 0; r < 4; r += 2) {
                const float hv0 = acc[i][j][r];
                const float hv1 = acc[i][j][r + 1];
                const unsigned pk = pk2(hv0, hv1);
                Hb[(size_t)(row0 + r) * DD + col] = (unsigned short)pk;
                Hb[(size_t)(row0 + r + 1) * DD + col] = (unsigned short)(pk >> 16);
                qp = fmaf(bf2f(nab[(size_t)(row0 + r) * DD + col]), hv0, qp);
                qp = fmaf(bf2f(nab[(size_t)(row0 + r + 1) * DD + col]), hv1, qp);
            }
        }
        qp += __shfl_xor(qp, 16);
        qp += __shfl_xor(qp, 32);
        if (quad == 0) atomicAdd(&qsum[wn * 32 + j * 16 + ln], qp);
    }
    __syncthreads();
    if (tid < 64) atomicAdd(q + bz * DD + e0 + tid, qsum[tid]);
}

// ---------------------------------------------------------------------------
// K4: persp via MFMA, split-K over 2 waves (wave w reduces k = w*256..+255).
//   s1 = (na*hv) @ W2^T, s2 = na^2 @ W2^T, s3 = hv^2 @ W2^T, hv = H*invq
//   out = s1 * rsqrt(max(s2,eps)) * rsqrt(max(s3,eps))
// grid: (T/16, B), 128 thr.  Wave1's partials combined through LDS by wave0.
// ---------------------------------------------------------------------------
__global__ __launch_bounds__(128)
void k_persp_mfma(const unsigned short* __restrict__ na,
                  const unsigned short* __restrict__ H,
                  const float* __restrict__ q,
                  const unsigned short* __restrict__ W2,
                  float* __restrict__ out) {
    const int b    = blockIdx.y;
    const int r0   = blockIdx.x * 16;
    const int wave = threadIdx.x >> 6;
    const int lane = threadIdx.x & 63;
    const int quad = lane >> 4, ln = lane & 15;
    const size_t rowbase = ((size_t)b * TT + r0 + ln) * DD;

    __shared__ float qs[DD];
    __shared__ float ps[64][24];     // wave1 partials: [lane][{s1,s2,s3}x{j}x{r}]
    {
        const float* qb = q + (size_t)b * DD;
        float4 v = *(const float4*)(qb + 4 * threadIdx.x);
        qs[4 * threadIdx.x + 0] = rsqrtf(fmaxf(v.x, EPSF));
        qs[4 * threadIdx.x + 1] = rsqrtf(fmaxf(v.y, EPSF));
        qs[4 * threadIdx.x + 2] = rsqrtf(fmaxf(v.z, EPSF));
        qs[4 * threadIdx.x + 3] = rsqrtf(fmaxf(v.w, EPSF));
    }
    __syncthreads();

    f32x4 s1[2], s2[2], s3[2];
#pragma unroll
    for (int j = 0; j < 2; ++j)
#pragma unroll
        for (int r = 0; r < 4; ++r) { s1[j][r] = 0.f; s2[j][r] = 0.f; s3[j][r] = 0.f; }

    const int kbeg = wave * 256;
    for (int k0 = kbeg; k0 < kbeg + 256; k0 += 32) {
        const int k = k0 + quad * 8;
        uint4 au = *(const uint4*)(na + rowbase + k);
        uint4 hu = *(const uint4*)(H + rowbase + k);
        float4 q0 = *(const float4*)&qs[k];
        float4 q1 = *(const float4*)&qs[k + 4];
        const float av[8] = {bf2f(au.x & 0xffffu), bf2f(au.x >> 16),
                             bf2f(au.y & 0xffffu), bf2f(au.y >> 16),
                             bf2f(au.z & 0xffffu), bf2f(au.z >> 16),
                             bf2f(au.w & 0xffffu), bf2f(au.w >> 16)};
        const float qv[8] = {q0.x, q0.y, q0.z, q0.w, q1.x, q1.y, q1.z, q1.w};
        float hv[8] = {bf2f(hu.x & 0xffffu), bf2f(hu.x >> 16),
                       bf2f(hu.y & 0xffffu), bf2f(hu.y >> 16),
                       bf2f(hu.z & 0xffffu), bf2f(hu.z >> 16),
                       bf2f(hu.w & 0xffffu), bf2f(hu.w >> 16)};
#pragma unroll
        for (int t = 0; t < 8; ++t) hv[t] *= qv[t];
        U8 ah, aa, hh;
        ah.u.x = pk2(av[0] * hv[0], av[1] * hv[1]);
        ah.u.y = pk2(av[2] * hv[2], av[3] * hv[3]);
        ah.u.z = pk2(av[4] * hv[4], av[5] * hv[5]);
        ah.u.w = pk2(av[6] * hv[6], av[7] * hv[7]);
        aa.u.x = pk2(av[0] * av[0], av[1] * av[1]);
        aa.u.y = pk2(av[2] * av[2], av[3] * av[3]);
        aa.u.z = pk2(av[4] * av[4], av[5] * av[5]);
        aa.u.w = pk2(av[6] * av[6], av[7] * av[7]);
        hh.u.x = pk2(hv[0] * hv[0], hv[1] * hv[1]);
        hh.u.y = pk2(hv[2] * hv[2], hv[3] * hv[3]);
        hh.u.z = pk2(hv[4] * hv[4], hv[5] * hv[5]);
        hh.u.w = pk2(hv[6] * hv[6], hv[7] * hv[7]);
        short8 bw0 = *(const short8*)(W2 + (size_t)ln * DD + k);
        short8 bw1 = *(const short8*)(W2 + (size_t)(16 + ln) * DD + k);
        s1[0] = __builtin_amdgcn_mfma_f32_16x16x32_bf16(ah.s, bw0, s1[0], 0, 0, 0);
        s1[1] = __builtin_amdgcn_mfma_f32_16x16x32_bf16(ah.s, bw1, s1[1], 0, 0, 0);
        s2[0] = __builtin_amdgcn_mfma_f32_16x16x32_bf16(aa.s, bw0, s2[0], 0, 0, 0);
        s2[1] = __builtin_amdgcn_mfma_f32_16x16x32_bf16(aa.s, bw1, s2[1], 0, 0, 0);
        s3[0] = __builtin_amdgcn_mfma_f32_16x16x32_bf16(hh.s, bw0, s3[0], 0, 0, 0);
        s3[1] = __builtin_amdgcn_mfma_f32_16x16x32_bf16(hh.s, bw1, s3[1], 0, 0, 0);
    }

    if (wave == 1) {
#pragma unroll
        for (int j = 0; j < 2; ++j)
#pragma unroll
            for (int r = 0; r < 4; ++r) {
                ps[lane][j * 4 + r]      = s1[j][r];
                ps[lane][8 + j * 4 + r]  = s2[j][r];
                ps[lane][16 + j * 4 + r] = s3[j][r];
            }
    }
    __syncthreads();
    if (wave == 0) {
#pragma unroll
        for (int j = 0; j < 2; ++j) {
            const int p = j * 16 + ln;
            if (p < PP) {
#pragma unroll
                for (int r = 0; r < 4; ++r) {
                    const float v1 = s1[j][r] + ps[lane][j * 4 + r];
                    const float v2 = s2[j][r] + ps[lane][8 + j * 4 + r];
                    const float v3 = s3[j][r] + ps[lane][16 + j * 4 + r];
                    const size_t row = (size_t)b * TT + r0 + quad * 4 + r;
                    const float v = v1 * rsqrtf(fmaxf(v2, EPSF))
                                       * rsqrtf(fmaxf(v3, EPSF));
                    out[row * PP + p] = v;
                    out[(size_t)BTP + row * PP + p] = v;
                }
            }
        }
    }
}

// ---------------------------------------------------------------------------
extern "C" void kernel_launch(void* const* d_in, const int* in_sizes, int n_in,
                              void* d_out, int out_size, void* d_ws, size_t ws_size,
                              hipStream_t stream) {
    (void)in_sizes; (void)n_in; (void)out_size; (void)ws_size;
    const float* a = (const float*)d_in[0];   // (B,T,D)
    const float* b = (const float*)d_in[1];   // (B,T,D)
    const float* W = (const float*)d_in[2];   // (P,D)
    float* out = (float*)d_out;

    char* ws = (char*)d_ws;
    unsigned short* nb_bf = (unsigned short*)ws;                       // 8 MB
    unsigned short* na_bf = (unsigned short*)(ws + (8u << 20));        // 8 MB
    unsigned short* G_bf  = (unsigned short*)(ws + (16u << 20));       // 4 MB
    unsigned short* H_bf  = (unsigned short*)(ws + (20u << 20));       // 8 MB
    float* q     = (float*)(ws + (28u << 20));                         // 64 KB
    unsigned short* W2 = (unsigned short*)(ws + (28u << 20) + (64u << 10)); // 32 KB

    // L1: norms + na/nb bf16 + q zero + W2 build
    k_prep<<<BB * TT / 4, 256, 0, stream>>>(a, b, W, na_bf, nb_bf, q, W2);

    // L2: G = nb nb^T   [BK=32]
    dim3 gG(4, 4, BB);
    k_gemm_g<<<gG, 256, 0, stream>>>(nb_bf, G_bf);

    // L3: H = G na (inline B-transpose staging), fused q accumulation
    dim3 gH(DD / 64, TT / 64, BB);
    k_gemm_h<<<gH, 256, 0, stream>>>(G_bf, na_bf, H_bf, q);

    // L4: perspective outputs (invq inlined, split-K over 2 waves)
    dim3 gP(TT / 16, BB);
    k_persp_mfma<<<gP, 128, 0, stream>>>(na_bf, H_bf, q, W2, out);
}